// Round 18
// baseline (79.210 us; speedup 1.0000x reference)
//
#include <hip/hip_runtime.h>

#define BB   64
#define S    2048
#define HH   128
#define KCH  682
#define EPS  1e-5f

// ===== MFMA path: one-term fp16, 512-thr blocks (4cg x 2ng), TT=96, LDS A-staging =====
#define TT2   96
#define NTB2  22          // ceil(2046/96)
#define NROWS 114         // rows rr: t = t0-3+rr

typedef __attribute__((ext_vector_type(8))) _Float16 f16x8;
typedef __attribute__((ext_vector_type(8))) unsigned short u16x8;
typedef __attribute__((ext_vector_type(4))) unsigned short u16x4;
typedef __attribute__((ext_vector_type(4))) float f32x4;

__device__ __forceinline__ unsigned short f2h(float v) {
    union { _Float16 h; unsigned short u; } c;
    c.h = (_Float16)v;              // round-to-nearest
    return c.u;
}

// Pack W fragments, single fp16 plane, MFMA A-order (row=lane&15, k=(lane>>4)*8+j).
// frag_idx = (mat*12+kb)*8+mc ; 512 ushort (1 KB) per frag. wpk = 288 KB.
__global__ void pack_w_frags(const float* __restrict__ w1, const float* __restrict__ w2,
                             const float* __restrict__ pw, unsigned short* __restrict__ wpk) {
    int u = blockIdx.x * 256 + threadIdx.x;     // 18432 units = 288 frags x 64 lanes
    if (u >= 18432) return;
    int lane = u & 63, mc = (u >> 6) & 7, kb = (u >> 9) % 12, mat = u / 6144;
    const float* src = (mat == 0) ? w1 : (mat == 1) ? w2 : pw;
    int c = mc * 16 + (lane & 15);
    int kbase = kb * 32 + ((lane >> 4) << 3);
    u16x8 hv;
    #pragma unroll
    for (int j = 0; j < 8; ++j) {
        int k = kbase + j, tap = k >> 7, ci = k & 127;   // K = tap*128 + ci
        hv[j] = f2h(src[c * 384 + ci * 3 + tap]);
    }
    *(u16x8*)(wpk + (size_t)((mat * 12 + kb) * 8 + mc) * 512 + lane * 8) = hv;
}

__device__ __forceinline__ int read_seqlen(const int* seq, int b) {
    bool is64 = true;
    for (int i = 1; i < 64; i += 2) { if (seq[i] != 0) { is64 = false; break; } }
    return is64 ? seq[2 * b] : seq[b];
}

// swizzled byte address into the [NROWS][128] fp16 plane: row rr, 16B-chunk index
__device__ __forceinline__ int haddr(int rr, int chunk) {
    return (rr << 8) | ((chunk ^ (rr & 15)) << 4);
}

// Conv with double-buffered LDS A-staging: wave wv stages frag (kb, mc=wv) each kb;
// all waves read their cg's 2 frags from LDS (ds_read_b128, conflict-free).
// Barrier per kb hands buffers over; in-flight global load spans the whole kb phase.
template<int NT>
__device__ __forceinline__ void conv_st(
        f32x4 (&acc)[2][NT], const unsigned short* __restrict__ wpk, int mat,
        const unsigned short* __restrict__ hH, unsigned short* __restrict__ aStage,
        int cg, int wv, int nt_base, int nt_lim, int rbase, int lane) {
    #pragma unroll
    for (int m = 0; m < 2; ++m)
        #pragma unroll
        for (int j = 0; j < NT; ++j) acc[m][j] = (f32x4){0.f, 0.f, 0.f, 0.f};

    const char* gb = (const char*)wpk + (size_t)(mat * 12) * 8192;
    // prologue: stage kb=0 into buf 0
    {
        uint4 t = *(const uint4*)(gb + (size_t)wv * 1024 + lane * 16);
        *(uint4*)((char*)aStage + wv * 1024 + lane * 16) = t;
    }
    __syncthreads();
    for (int kb = 0; kb < 12; ++kb) {
        const int buf = kb & 1;
        const bool more = (kb < 11);
        uint4 tnext;
        if (more)   // issue next-kb stage load early; latency hides under this kb's compute
            tnext = *(const uint4*)(gb + (size_t)(kb + 1) * 8192 + (size_t)wv * 1024 + lane * 16);
        f16x8 a0 = *(const f16x8*)((const char*)aStage + buf * 8192 + (cg * 2 + 0) * 1024 + lane * 16);
        f16x8 a1 = *(const f16x8*)((const char*)aStage + buf * 8192 + (cg * 2 + 1) * 1024 + lane * 16);
        const int tap = kb >> 2;
        const int chunk = (kb & 3) * 4 + (lane >> 4);
        const int rr0 = rbase + tap + (lane & 15);
        __builtin_amdgcn_s_setprio(1);
        #pragma unroll
        for (int j = 0; j < NT; ++j) {
            const int nt = nt_base + j;            // wave-uniform guard
            if (nt < nt_lim) {
                const int ad = haddr(rr0 + nt * 16, chunk);
                f16x8 bh = *(const f16x8*)((const char*)hH + ad);
                acc[0][j] = __builtin_amdgcn_mfma_f32_16x16x32_f16(a0, bh, acc[0][j], 0, 0, 0);
                acc[1][j] = __builtin_amdgcn_mfma_f32_16x16x32_f16(a1, bh, acc[1][j], 0, 0, 0);
            }
        }
        __builtin_amdgcn_s_setprio(0);
        if (more)   // write-late: vmcnt drain lands here, after compute
            *(uint4*)((char*)aStage + (buf ^ 1) * 8192 + wv * 1024 + lane * 16) = tnext;
        __syncthreads();
    }
}

// BN+relu epilogue: output tt=(nt_base+j)*16+(lane&15), t=t0+T_OFF+tt, row rr=tt+ROW_OFF
template<int NT, int ROW_OFF, int T_OFF>
__device__ __forceinline__ void epi_f16(
        f32x4 (&acc)[2][NT], const float* __restrict__ bias,
        const float* __restrict__ bng, const float* __restrict__ bnb,
        const float* __restrict__ bnm, const float* __restrict__ bnv, int layer,
        unsigned short* __restrict__ hH, int cg, int nt_base, int nt_lim,
        int lane, int t0) {
    #pragma unroll
    for (int m = 0; m < 2; ++m) {
        const int c0 = (cg * 2 + m) * 16 + (lane >> 4) * 4;
        const float4 bv = *(const float4*)&bias[c0];
        const float4 g  = *(const float4*)&bng[layer * 128 + c0];
        const float4 be = *(const float4*)&bnb[layer * 128 + c0];
        const float4 mn = *(const float4*)&bnm[layer * 128 + c0];
        const float4 vr = *(const float4*)&bnv[layer * 128 + c0];
        const float av[4] = { g.x * rsqrtf(vr.x + EPS), g.y * rsqrtf(vr.y + EPS),
                              g.z * rsqrtf(vr.z + EPS), g.w * rsqrtf(vr.w + EPS) };
        const float dv[4] = { be.x - mn.x * av[0], be.y - mn.y * av[1],
                              be.z - mn.z * av[2], be.w - mn.w * av[3] };
        const float bb[4] = { bv.x, bv.y, bv.z, bv.w };
        const int byte = c0 * 2, chunk = byte >> 4, off = byte & 15;
        #pragma unroll
        for (int j = 0; j < NT; ++j) {
            const int nt = nt_base + j;
            if (nt < nt_lim) {
                const int tt = nt * 16 + (lane & 15);
                const int t = t0 + T_OFF + tt;
                const int rr = tt + ROW_OFF;
                const bool ok = (t >= 0) && (t < S);
                u16x4 h4;
                #pragma unroll
                for (int r = 0; r < 4; ++r) {
                    float v = 0.f;
                    if (ok) v = fmaf(fmaxf(acc[m][j][r] + bb[r], 0.f), av[r], dv[r]);
                    h4[r] = f2h(v);
                }
                *(u16x4*)((char*)hH + (haddr(rr, chunk) | off)) = h4;
            }
        }
    }
}

__global__ __launch_bounds__(512, 6)
void fused_mfma(const float* __restrict__ x, const int* __restrict__ seq,
                const float* __restrict__ w0, const float* __restrict__ b0,
                const float* __restrict__ b1, const float* __restrict__ b2,
                const float* __restrict__ bng, const float* __restrict__ bnb,
                const float* __restrict__ bnm, const float* __restrict__ bnv,
                const float* __restrict__ pb, const float* __restrict__ fcw,
                const float* __restrict__ fcb, const unsigned short* __restrict__ wpk,
                float* __restrict__ out) {
    __shared__ __align__(16) unsigned short hH[NROWS * 128];    // 29184 B
    __shared__ __align__(16) unsigned short aStage[2][4096];    // 16384 B A-frag dbuf
    __shared__ __align__(16) float xs[116];
    __shared__ float p0[6 * 128];
    __shared__ float zred[4][2][16];
    __shared__ int nch_s;

    const int tid = threadIdx.x;
    const int lane = tid & 63, wv = tid >> 6;
    const int cg = wv & 3, ng = wv >> 2;      // 4 c-groups x 2 n-groups
    const int b  = blockIdx.x / NTB2;
    const int jt = blockIdx.x - b * NTB2;
    const int t0 = jt * TT2;

    // ---- stage x (t0-4 .. t0+111) + conv0/bn0 per-channel constants ----
    if (tid < 116) {
        const int t = t0 - 4 + tid;
        xs[tid] = (t >= 0 && t < S) ? x[b * S + t] : 0.f;
    }
    if (tid < 128) {
        const int c = tid;
        p0[c]         = w0[c * 3 + 0];
        p0[128 + c]   = w0[c * 3 + 1];
        p0[2*128 + c] = w0[c * 3 + 2];
        p0[3*128 + c] = b0[c];
        const float a0 = bng[c] * rsqrtf(bnv[c] + EPS);
        p0[4*128 + c] = a0;
        p0[5*128 + c] = bnb[c] - bnm[c] * a0;
    }
    if (tid == 0) nch_s = read_seqlen(seq, b) / 3;
    __syncthreads();

    // ---- conv0 + bn0 -> h1 rows rr=0..113 (t = t0-3+rr), single fp16 ----
    for (int it = 0; it < 4; ++it) {
        const int u = tid + it * 512;              // 1824 units = 114 rows x 16 octets
        if (u < NROWS * 16) {
            const int rr = u >> 4, oct = u & 15, ci0 = oct * 8;
            const int t = t0 - 3 + rr;
            const bool ok = (t >= 0) && (t < S);
            const float xm = xs[rr], xc = xs[rr + 1], xp = xs[rr + 2];
            u16x8 hv;
            #pragma unroll
            for (int q = 0; q < 8; ++q) {
                const int c = ci0 + q;
                float v = 0.f;
                if (ok) {
                    float sa = fmaf(xp, p0[2*128 + c],
                               fmaf(xc, p0[128 + c],
                               fmaf(xm, p0[c], p0[3*128 + c])));
                    v = fmaf(fmaxf(sa, 0.f), p0[4*128 + c], p0[5*128 + c]);
                }
                hv[q] = f2h(v);
            }
            *(u16x8*)((char*)hH + haddr(rr, oct)) = hv;
        }
    }
    __syncthreads();

    // ---- conv1: 7 n-tiles (tt 0..111 -> rows 1..112); ng0 {0..3}, ng1 {4..6} ----
    {
        f32x4 acc1[2][4];
        conv_st<4>(acc1, wpk, 0, hH, &aStage[0][0], cg, wv, ng * 4, 7, 0, lane);
        // conv_st's trailing barrier guarantees all h1 reads done
        epi_f16<4, 1, -2>(acc1, b1, bng, bnb, bnm, bnv, 1, hH, cg, ng * 4, 7, lane, t0);
    }
    __syncthreads();

    // ---- conv2: 6 n-tiles (tt 0..95 -> rows 3..98); B rows 2..99; ng0 {0..2}, ng1 {3..5} ----
    {
        f32x4 acc2[2][3];
        conv_st<3>(acc2, wpk, 1, hH, &aStage[0][0], cg, wv, ng * 3, 6, 2, lane);
        epi_f16<3, 3, 0>(acc2, b2, bng, bnb, bnm, bnv, 2, hH, cg, ng * 3, 6, lane, t0);
    }
    __syncthreads();

    // ---- pre einsum: 32 chunks; ng owns k-tile (k = 16ng + (lane&15)); rows 3+3k+tap ----
    f32x4 pacc[2];
    pacc[0] = (f32x4){0.f, 0.f, 0.f, 0.f};
    pacc[1] = (f32x4){0.f, 0.f, 0.f, 0.f};
    {
        const char* gb = (const char*)wpk + (size_t)(2 * 12) * 8192;
        const int klocal = ng * 16 + (lane & 15);
        // prologue: stage kb=0 into buf 0
        {
            uint4 t = *(const uint4*)(gb + (size_t)wv * 1024 + lane * 16);
            *(uint4*)((char*)aStage + wv * 1024 + lane * 16) = t;
        }
        __syncthreads();
        for (int kb = 0; kb < 12; ++kb) {
            const int buf = kb & 1;
            const bool more = (kb < 11);
            uint4 tnext;
            if (more)
                tnext = *(const uint4*)(gb + (size_t)(kb + 1) * 8192 + (size_t)wv * 1024 + lane * 16);
            f16x8 a0 = *(const f16x8*)((const char*)aStage + buf * 8192 + (cg * 2 + 0) * 1024 + lane * 16);
            f16x8 a1 = *(const f16x8*)((const char*)aStage + buf * 8192 + (cg * 2 + 1) * 1024 + lane * 16);
            const int tap = kb >> 2;
            const int chunk = (kb & 3) * 4 + (lane >> 4);
            const int rr = 3 + 3 * klocal + tap;          // h3 row for t = t0+3k+tap
            const int ad = haddr(rr, chunk);
            f16x8 bh = *(const f16x8*)((const char*)hH + ad);
            __builtin_amdgcn_s_setprio(1);
            pacc[0] = __builtin_amdgcn_mfma_f32_16x16x32_f16(a0, bh, pacc[0], 0, 0, 0);
            pacc[1] = __builtin_amdgcn_mfma_f32_16x16x32_f16(a1, bh, pacc[1], 0, 0, 0);
            __builtin_amdgcn_s_setprio(0);
            if (more)
                *(uint4*)((char*)aStage + (buf ^ 1) * 8192 + wv * 1024 + lane * 16) = tnext;
            __syncthreads();
        }
    }

    // ---- relu(z+pb)*fcw, reduce over this wave's 32 o-channels ----
    float s0 = 0.f;
    #pragma unroll
    for (int m = 0; m < 2; ++m) {
        const int o0 = (cg * 2 + m) * 16 + (lane >> 4) * 4;
        const float4 pbv = *(const float4*)&pb[o0];
        const float4 fwv = *(const float4*)&fcw[o0];
        const float pbb[4] = { pbv.x, pbv.y, pbv.z, pbv.w };
        const float fww[4] = { fwv.x, fwv.y, fwv.z, fwv.w };
        #pragma unroll
        for (int r = 0; r < 4; ++r)
            s0 += fmaxf(pacc[m][r] + pbb[r], 0.f) * fww[r];
    }
    s0 += __shfl_xor(s0, 16);
    s0 += __shfl_xor(s0, 32);
    if (lane < 16) zred[cg][ng][lane] = s0;        // k = 16ng + lane
    __syncthreads();
    if (tid < 32) {
        const int kt = tid >> 4, kl = tid & 15;
        const float zz = zred[0][kt][kl] + zred[1][kt][kl]
                       + zred[2][kt][kl] + zred[3][kt][kl];
        const int kG = jt * 32 + tid;
        if (kG < KCH)
            out[b * KCH + kG] = (kG < nch_s) ? (zz + fcb[0]) : 0.f;
    }
}

// ================= fp32 fallback (round-3 verified) =================
#define TT   78
#define NTB  27
#define STRIDE 84

__device__ __forceinline__ void stage_w_fb(float* __restrict__ wtS,
                                           const float* __restrict__ wraw, int cc, int tid) {
    for (int i = tid; i < 6144; i += 256)
        wtS[i] = wraw[(i & 127) * 384 + cc * 3 + (i >> 7)];
}

__device__ __forceinline__ void conv_gemm_fb(float (&acc)[10][4],
                                             const float* __restrict__ wraw,
                                             const float* __restrict__ hAp,
                                             float* __restrict__ wtS,
                                             int tid, int c0, int tbase) {
    #pragma unroll
    for (int i = 0; i < 10; ++i)
        #pragma unroll
        for (int q = 0; q < 4; ++q) acc[i][q] = 0.f;
    for (int cc = 0; cc < HH; cc += 16) {
        __syncthreads();
        stage_w_fb(wtS, wraw, cc, tid);
        __syncthreads();
        for (int ci = 0; ci < 16; ++ci) {
            float hr[12];
            #pragma unroll
            for (int j = 0; j < 12; ++j) hr[j] = hAp[(cc + ci) * STRIDE + tbase + j];
            #pragma unroll
            for (int tap = 0; tap < 3; ++tap) {
                const float4 w = *(const float4*)&wtS[((ci * 3 + tap) << 7) + c0];
                #pragma unroll
                for (int i = 0; i < 10; ++i) {
                    const float h = hr[i + tap];
                    acc[i][0] = fmaf(h, w.x, acc[i][0]);
                    acc[i][1] = fmaf(h, w.y, acc[i][1]);
                    acc[i][2] = fmaf(h, w.z, acc[i][2]);
                    acc[i][3] = fmaf(h, w.w, acc[i][3]);
                }
            }
        }
    }
}

__global__ __launch_bounds__(256, 2)
void fused_pd(const float* __restrict__ x, const int* __restrict__ seq,
              const float* __restrict__ w0, const float* __restrict__ b0,
              const float* __restrict__ w1raw, const float* __restrict__ b1,
              const float* __restrict__ w2raw, const float* __restrict__ b2,
              const float* __restrict__ bng, const float* __restrict__ bnb,
              const float* __restrict__ bnm, const float* __restrict__ bnv,
              const float* __restrict__ pwraw, const float* __restrict__ pb,
              const float* __restrict__ fcw, const float* __restrict__ fcb,
              float* __restrict__ out) {
    __shared__ __align__(16) float hA[HH * STRIDE];
    __shared__ __align__(16) float wtS[6144];
    __shared__ __align__(16) float xsf[TT + 8];
    __shared__ int nch_s;

    const int tid = threadIdx.x;
    const int b  = blockIdx.x / NTB;
    const int jt = blockIdx.x - b * NTB;
    const int t0 = jt * TT;

    for (int j = tid; j < TT + 6; j += 256) {
        const int t = t0 - 3 + j;
        xsf[j] = (t >= 0 && t < S) ? x[b * S + t] : 0.f;
    }
    if (tid == 0) nch_s = read_seqlen(seq, b) / 3;

    const int cch = tid & 127;
    const float w0a = w0[cch * 3 + 0], w0b = w0[cch * 3 + 1], w0c = w0[cch * 3 + 2];
    const float bb0 = b0[cch];
    const float a0 = bng[cch] * rsqrtf(bnv[cch] + EPS);
    const float d0 = bnb[cch] - bnm[cch] * a0;
    __syncthreads();

    for (int i = tid; i < (TT + 4) * HH; i += 256) {
        const int ttl = i >> 7;
        const int t = t0 - 2 + ttl;
        float v = 0.f;
        if (t >= 0 && t < S) {
            float sa = fmaf(xsf[ttl + 2], w0c, fmaf(xsf[ttl + 1], w0b, fmaf(xsf[ttl], w0a, bb0)));
            v = fmaf(fmaxf(sa, 0.f), a0, d0);
        }
        hA[cch * STRIDE + ttl] = v;
    }

    const int cg = tid & 31, tg = tid >> 5;
    const int c0 = cg * 4;
    const int tbase = tg * 10;
    float acc[10][4];

    conv_gemm_fb(acc, w1raw, hA, wtS, tid, c0, tbase);
    {
        const float4 bv = *(const float4*)&b1[c0];
        const float4 g  = *(const float4*)&bng[HH + c0];
        const float4 be = *(const float4*)&bnb[HH + c0];
        const float4 mn = *(const float4*)&bnm[HH + c0];
        const float4 vr = *(const float4*)&bnv[HH + c0];
        float av[4] = { g.x * rsqrtf(vr.x + EPS), g.y * rsqrtf(vr.y + EPS),
                        g.z * rsqrtf(vr.z + EPS), g.w * rsqrtf(vr.w + EPS) };
        float dv[4] = { be.x - mn.x * av[0], be.y - mn.y * av[1],
                        be.z - mn.z * av[2], be.w - mn.w * av[3] };
        float bb[4] = { bv.x, bv.y, bv.z, bv.w };
        __syncthreads();
        #pragma unroll
        for (int i = 0; i < 10; ++i) {
            const int tt2 = tbase + i;
            const int t = t0 - 1 + tt2;
            const bool ok = (t >= 0) && (t < S);
            #pragma unroll
            for (int q = 0; q < 4; ++q) {
                float v = 0.f;
                if (ok) v = fmaf(fmaxf(acc[i][q] + bb[q], 0.f), av[q], dv[q]);
                hA[(c0 + q) * STRIDE + tt2] = v;
            }
        }
        __syncthreads();
    }

    conv_gemm_fb(acc, w2raw, hA, wtS, tid, c0, tbase);
    {
        const float4 bv = *(const float4*)&b2[c0];
        const float4 g  = *(const float4*)&bng[2 * HH + c0];
        const float4 be = *(const float4*)&bnb[2 * HH + c0];
        const float4 mn = *(const float4*)&bnm[2 * HH + c0];
        const float4 vr = *(const float4*)&bnv[2 * HH + c0];
        float av[4] = { g.x * rsqrtf(vr.x + EPS), g.y * rsqrtf(vr.y + EPS),
                        g.z * rsqrtf(vr.z + EPS), g.w * rsqrtf(vr.w + EPS) };
        float dv[4] = { be.x - mn.x * av[0], be.y - mn.y * av[1],
                        be.z - mn.z * av[2], be.w - mn.w * av[3] };
        float bb[4] = { bv.x, bv.y, bv.z, bv.w };
        __syncthreads();
        #pragma unroll
        for (int i = 0; i < 10; ++i) {
            const int tt3 = tbase + i;
            if (tt3 < TT) {
                const int t = t0 + tt3;
                #pragma unroll
                for (int q = 0; q < 4; ++q) {
                    float vv = 0.f;
                    if (t < S) vv = fmaf(fmaxf(acc[i][q] + bb[q], 0.f), av[q], dv[q]);
                    hA[(c0 + q) * STRIDE + tt3] = vv;
                }
            }
        }
        __syncthreads();
    }

    const int og = tid & 31, kg = tid >> 5;
    const int oo = og * 4;
    float pacc[4][4];
    #pragma unroll
    for (int j = 0; j < 4; ++j)
        #pragma unroll
        for (int q = 0; q < 4; ++q) pacc[j][q] = 0.f;

    for (int hc = 0; hc < HH; hc += 16) {
        __syncthreads();
        stage_w_fb(wtS, pwraw, hc, tid);
        __syncthreads();
        for (int h = 0; h < 16; ++h) {
            #pragma unroll
            for (int tap = 0; tap < 3; ++tap) {
                const float4 w = *(const float4*)&wtS[((h * 3 + tap) << 7) + oo];
                #pragma unroll
                for (int j = 0; j < 4; ++j) {
                    int kl = kg * 4 + j; kl = (kl > 25) ? 25 : kl;
                    const float hv = hA[(hc + h) * STRIDE + 3 * kl + tap];
                    pacc[j][0] = fmaf(hv, w.x, pacc[j][0]);
                    pacc[j][1] = fmaf(hv, w.y, pacc[j][1]);
                    pacc[j][2] = fmaf(hv, w.z, pacc[j][2]);
                    pacc[j][3] = fmaf(hv, w.w, pacc[j][3]);
                }
            }
        }
    }

    const float fcb0 = fcb[0];
    const float4 pbv = *(const float4*)&pb[oo];
    const float4 fwv = *(const float4*)&fcw[oo];
    const int nch = nch_s;
    #pragma unroll
    for (int j = 0; j < 4; ++j) {
        float s = fmaxf(pacc[j][0] + pbv.x, 0.f) * fwv.x
                + fmaxf(pacc[j][1] + pbv.y, 0.f) * fwv.y
                + fmaxf(pacc[j][2] + pbv.z, 0.f) * fwv.z
                + fmaxf(pacc[j][3] + pbv.w, 0.f) * fwv.w;
        #pragma unroll
        for (int m = 1; m < 32; m <<= 1) s += __shfl_xor(s, m, 64);
        if (og == 0) {
            const int kl = kg * 4 + j;
            const int kG = jt * 26 + kl;
            if (kl < 26 && kG < KCH)
                out[b * KCH + kG] = (kG < nch) ? (s + fcb0) : 0.f;
        }
    }
}

extern "C" void kernel_launch(void* const* d_in, const int* in_sizes, int n_in,
                              void* d_out, int out_size, void* d_ws, size_t ws_size,
                              hipStream_t stream) {
    (void)in_sizes; (void)n_in; (void)out_size;
    const float* x    = (const float*)d_in[0];
    const int*   seq  = (const int*)d_in[1];
    const float* w0   = (const float*)d_in[2];
    const float* b0   = (const float*)d_in[3];
    const float* w1   = (const float*)d_in[4];
    const float* b1   = (const float*)d_in[5];
    const float* w2   = (const float*)d_in[6];
    const float* b2   = (const float*)d_in[7];
    const float* bng  = (const float*)d_in[8];
    const float* bnb  = (const float*)d_in[9];
    const float* bnm  = (const float*)d_in[10];
    const float* bnv  = (const float*)d_in[11];
    const float* pw   = (const float*)d_in[12];
    const float* pb   = (const float*)d_in[13];
    const float* fcw  = (const float*)d_in[14];
    const float* fcb  = (const float*)d_in[15];
    float* out = (float*)d_out;

    const size_t need = (size_t)3 * 12 * 8 * 1024;   // 294912 B of packed frags
    if (ws_size >= need) {
        unsigned short* wpk = (unsigned short*)d_ws;
        pack_w_frags<<<72, 256, 0, stream>>>(w1, w2, pw, wpk);
        fused_mfma<<<BB * NTB2, 512, 0, stream>>>(x, seq, w0, b0, b1, b2,
                                                  bng, bnb, bnm, bnv,
                                                  pb, fcw, fcb, wpk, out);
    } else {
        fused_pd<<<BB * NTB, 256, 0, stream>>>(x, seq, w0, b0, w1, b1, w2, b2,
                                               bng, bnb, bnm, bnv, pw, pb, fcw, fcb,
                                               out);
    }
}

// Round 19
// 77.555 us; speedup vs baseline: 1.0213x; 1.0213x over previous
//
#include <hip/hip_runtime.h>

#define BB   64
#define S    2048
#define HH   128
#define KCH  682
#define EPS  1e-5f

// ===== MFMA path: one-term fp16 W + fp16 h, 512-thr blocks (4cg x 2ng waves), TT=96 =====
// Final configuration (r9, reproduced r17): 77.6 us, 6.6x over fp32 baseline.
// A/B-verified design notes:
//  - per-wave tiling 2mc x <=4nt is a sharp optimum (Tc=4 spills A-traffic, r10;
//    TT=120 lengthens phases, r14; A-prefetch adds movs, r13)
//  - VGPR32+AGPR32 = exactly the 64-reg / 8-wave-per-SIMD boundary; do not grow
//  - A-traffic & barriers are NOT the wall (r18: FETCH 13MB->2.5MB, time flat)
#define TT2   96
#define NTB2  22          // ceil(2046/96)
#define NROWS 114         // rows rr: t = t0-3+rr

typedef __attribute__((ext_vector_type(8))) _Float16 f16x8;
typedef __attribute__((ext_vector_type(8))) unsigned short u16x8;
typedef __attribute__((ext_vector_type(4))) unsigned short u16x4;
typedef __attribute__((ext_vector_type(4))) float f32x4;

__device__ __forceinline__ unsigned short f2h(float v) {
    union { _Float16 h; unsigned short u; } c;
    c.h = (_Float16)v;              // round-to-nearest
    return c.u;
}

// Pack W fragments, single fp16 plane, MFMA A-order (row=lane&15, k=(lane>>4)*8+j).
// frag_idx = (mat*12+kb)*8+mc ; 512 ushort per frag. wpk = 288 KB.
__global__ void pack_w_frags(const float* __restrict__ w1, const float* __restrict__ w2,
                             const float* __restrict__ pw, unsigned short* __restrict__ wpk) {
    int u = blockIdx.x * 256 + threadIdx.x;     // 18432 units = 288 frags x 64 lanes
    if (u >= 18432) return;
    int lane = u & 63, mc = (u >> 6) & 7, kb = (u >> 9) % 12, mat = u / 6144;
    const float* src = (mat == 0) ? w1 : (mat == 1) ? w2 : pw;
    int c = mc * 16 + (lane & 15);
    int kbase = kb * 32 + ((lane >> 4) << 3);
    u16x8 hv;
    #pragma unroll
    for (int j = 0; j < 8; ++j) {
        int k = kbase + j, tap = k >> 7, ci = k & 127;   // K = tap*128 + ci
        hv[j] = f2h(src[c * 384 + ci * 3 + tap]);
    }
    *(u16x8*)(wpk + (size_t)((mat * 12 + kb) * 8 + mc) * 512 + lane * 8) = hv;
}

__device__ __forceinline__ int read_seqlen(const int* seq, int b) {
    bool is64 = true;
    for (int i = 1; i < 64; i += 2) { if (seq[i] != 0) { is64 = false; break; } }
    return is64 ? seq[2 * b] : seq[b];
}

// swizzled byte address into the [NROWS][128] fp16 plane: row rr, 16B-chunk index
__device__ __forceinline__ int haddr(int rr, int chunk) {
    return (rr << 8) | ((chunk ^ (rr & 15)) << 4);
}

// C=2 mc-tiles (by cg), up to NT n-tiles; B rows = rbase + tap + (lane&15) + nt*16.
// One A-term: 1 B-read -> 2 MFMAs.
template<int NT>
__device__ __forceinline__ void conv_f16(
        f32x4 (&acc)[2][NT], const unsigned short* __restrict__ wpk, int mat,
        const unsigned short* __restrict__ hH, int cg, int nt_base, int nt_lim,
        int rbase, int lane) {
    #pragma unroll
    for (int m = 0; m < 2; ++m)
        #pragma unroll
        for (int j = 0; j < NT; ++j) acc[m][j] = (f32x4){0.f, 0.f, 0.f, 0.f};

    const f16x8* wp = (const f16x8*)wpk;
    for (int kb = 0; kb < 12; ++kb) {
        const int fb = (mat * 12 + kb) * 8 + cg * 2;
        f16x8 a0 = wp[(size_t)(fb + 0) * 64 + lane];
        f16x8 a1 = wp[(size_t)(fb + 1) * 64 + lane];
        const int tap = kb >> 2;
        const int chunk = (kb & 3) * 4 + (lane >> 4);
        const int rr0 = rbase + tap + (lane & 15);
        __builtin_amdgcn_s_setprio(1);
        #pragma unroll
        for (int j = 0; j < NT; ++j) {
            const int nt = nt_base + j;            // wave-uniform guard
            if (nt < nt_lim) {
                const int ad = haddr(rr0 + nt * 16, chunk);
                f16x8 bh = *(const f16x8*)((const char*)hH + ad);
                acc[0][j] = __builtin_amdgcn_mfma_f32_16x16x32_f16(a0, bh, acc[0][j], 0, 0, 0);
                acc[1][j] = __builtin_amdgcn_mfma_f32_16x16x32_f16(a1, bh, acc[1][j], 0, 0, 0);
            }
        }
        __builtin_amdgcn_s_setprio(0);
    }
}

// BN+relu epilogue: output tt=(nt_base+j)*16+(lane&15), t=t0+T_OFF+tt, row rr=tt+ROW_OFF
template<int NT, int ROW_OFF, int T_OFF>
__device__ __forceinline__ void epi_f16(
        f32x4 (&acc)[2][NT], const float* __restrict__ bias,
        const float* __restrict__ bng, const float* __restrict__ bnb,
        const float* __restrict__ bnm, const float* __restrict__ bnv, int layer,
        unsigned short* __restrict__ hH, int cg, int nt_base, int nt_lim,
        int lane, int t0) {
    #pragma unroll
    for (int m = 0; m < 2; ++m) {
        const int c0 = (cg * 2 + m) * 16 + (lane >> 4) * 4;
        const float4 bv = *(const float4*)&bias[c0];
        const float4 g  = *(const float4*)&bng[layer * 128 + c0];
        const float4 be = *(const float4*)&bnb[layer * 128 + c0];
        const float4 mn = *(const float4*)&bnm[layer * 128 + c0];
        const float4 vr = *(const float4*)&bnv[layer * 128 + c0];
        const float av[4] = { g.x * rsqrtf(vr.x + EPS), g.y * rsqrtf(vr.y + EPS),
                              g.z * rsqrtf(vr.z + EPS), g.w * rsqrtf(vr.w + EPS) };
        const float dv[4] = { be.x - mn.x * av[0], be.y - mn.y * av[1],
                              be.z - mn.z * av[2], be.w - mn.w * av[3] };
        const float bb[4] = { bv.x, bv.y, bv.z, bv.w };
        const int byte = c0 * 2, chunk = byte >> 4, off = byte & 15;
        #pragma unroll
        for (int j = 0; j < NT; ++j) {
            const int nt = nt_base + j;
            if (nt < nt_lim) {
                const int tt = nt * 16 + (lane & 15);
                const int t = t0 + T_OFF + tt;
                const int rr = tt + ROW_OFF;
                const bool ok = (t >= 0) && (t < S);
                u16x4 h4;
                #pragma unroll
                for (int r = 0; r < 4; ++r) {
                    float v = 0.f;
                    if (ok) v = fmaf(fmaxf(acc[m][j][r] + bb[r], 0.f), av[r], dv[r]);
                    h4[r] = f2h(v);
                }
                *(u16x4*)((char*)hH + (haddr(rr, chunk) | off)) = h4;
            }
        }
    }
}

__global__ __launch_bounds__(512, 8)
void fused_mfma(const float* __restrict__ x, const int* __restrict__ seq,
                const float* __restrict__ w0, const float* __restrict__ b0,
                const float* __restrict__ b1, const float* __restrict__ b2,
                const float* __restrict__ bng, const float* __restrict__ bnb,
                const float* __restrict__ bnm, const float* __restrict__ bnv,
                const float* __restrict__ pb, const float* __restrict__ fcw,
                const float* __restrict__ fcb, const unsigned short* __restrict__ wpk,
                float* __restrict__ out) {
    __shared__ __align__(16) unsigned short hH[NROWS * 128];    // 29184 B
    __shared__ __align__(16) float xs[116];
    __shared__ float p0[6 * 128];
    __shared__ float zred[4][2][16];
    __shared__ int nch_s;

    const int tid = threadIdx.x;
    const int lane = tid & 63, wv = tid >> 6;
    const int cg = wv & 3, ng = wv >> 2;      // 4 c-groups x 2 n-groups
    const int b  = blockIdx.x / NTB2;
    const int jt = blockIdx.x - b * NTB2;
    const int t0 = jt * TT2;

    // ---- stage x (t0-4 .. t0+111) + conv0/bn0 per-channel constants ----
    if (tid < 116) {
        const int t = t0 - 4 + tid;
        xs[tid] = (t >= 0 && t < S) ? x[b * S + t] : 0.f;
    }
    if (tid < 128) {
        const int c = tid;
        p0[c]         = w0[c * 3 + 0];
        p0[128 + c]   = w0[c * 3 + 1];
        p0[2*128 + c] = w0[c * 3 + 2];
        p0[3*128 + c] = b0[c];
        const float a0 = bng[c] * rsqrtf(bnv[c] + EPS);
        p0[4*128 + c] = a0;
        p0[5*128 + c] = bnb[c] - bnm[c] * a0;
    }
    if (tid == 0) nch_s = read_seqlen(seq, b) / 3;
    __syncthreads();

    // ---- conv0 + bn0 -> h1 rows rr=0..113 (t = t0-3+rr), single fp16 ----
    for (int it = 0; it < 4; ++it) {
        const int u = tid + it * 512;              // 1824 units = 114 rows x 16 octets
        if (u < NROWS * 16) {
            const int rr = u >> 4, oct = u & 15, ci0 = oct * 8;
            const int t = t0 - 3 + rr;
            const bool ok = (t >= 0) && (t < S);
            const float xm = xs[rr], xc = xs[rr + 1], xp = xs[rr + 2];
            u16x8 hv;
            #pragma unroll
            for (int q = 0; q < 8; ++q) {
                const int c = ci0 + q;
                float v = 0.f;
                if (ok) {
                    float sa = fmaf(xp, p0[2*128 + c],
                               fmaf(xc, p0[128 + c],
                               fmaf(xm, p0[c], p0[3*128 + c])));
                    v = fmaf(fmaxf(sa, 0.f), p0[4*128 + c], p0[5*128 + c]);
                }
                hv[q] = f2h(v);
            }
            *(u16x8*)((char*)hH + haddr(rr, oct)) = hv;
        }
    }
    __syncthreads();

    // ---- conv1: 7 n-tiles (tt 0..111 -> rows 1..112); ng0 {0..3}, ng1 {4..6} ----
    {
        f32x4 acc1[2][4];
        conv_f16<4>(acc1, wpk, 0, hH, cg, ng * 4, 7, 0, lane);
        __syncthreads();                            // all h1 reads done
        epi_f16<4, 1, -2>(acc1, b1, bng, bnb, bnm, bnv, 1, hH, cg, ng * 4, 7, lane, t0);
    }
    __syncthreads();

    // ---- conv2: 6 n-tiles (tt 0..95 -> rows 3..98); B rows 2..99; ng0 {0..2}, ng1 {3..5} ----
    {
        f32x4 acc2[2][3];
        conv_f16<3>(acc2, wpk, 1, hH, cg, ng * 3, 6, 2, lane);
        __syncthreads();                            // all h2 reads done
        epi_f16<3, 3, 0>(acc2, b2, bng, bnb, bnm, bnv, 2, hH, cg, ng * 3, 6, lane, t0);
    }
    __syncthreads();

    // ---- pre einsum: 32 chunks; ng owns k-tile (k = 16ng + (lane&15)); rows 3+3k+tap ----
    f32x4 pacc[2];
    pacc[0] = (f32x4){0.f, 0.f, 0.f, 0.f};
    pacc[1] = (f32x4){0.f, 0.f, 0.f, 0.f};
    {
        const f16x8* wp = (const f16x8*)wpk;
        const int klocal = ng * 16 + (lane & 15);
        for (int kb = 0; kb < 12; ++kb) {
            const int fb = (2 * 12 + kb) * 8 + cg * 2;
            f16x8 a0 = wp[(size_t)(fb + 0) * 64 + lane];
            f16x8 a1 = wp[(size_t)(fb + 1) * 64 + lane];
            const int tap = kb >> 2;
            const int chunk = (kb & 3) * 4 + (lane >> 4);
            const int rr = 3 + 3 * klocal + tap;          // h3 row for t = t0+3k+tap
            const int ad = haddr(rr, chunk);
            f16x8 bh = *(const f16x8*)((const char*)hH + ad);
            __builtin_amdgcn_s_setprio(1);
            pacc[0] = __builtin_amdgcn_mfma_f32_16x16x32_f16(a0, bh, pacc[0], 0, 0, 0);
            pacc[1] = __builtin_amdgcn_mfma_f32_16x16x32_f16(a1, bh, pacc[1], 0, 0, 0);
            __builtin_amdgcn_s_setprio(0);
        }
    }

    // ---- relu(z+pb)*fcw, reduce over this wave's 32 o-channels ----
    float s0 = 0.f;
    #pragma unroll
    for (int m = 0; m < 2; ++m) {
        const int o0 = (cg * 2 + m) * 16 + (lane >> 4) * 4;
        const float4 pbv = *(const float4*)&pb[o0];
        const float4 fwv = *(const float4*)&fcw[o0];
        const float pbb[4] = { pbv.x, pbv.y, pbv.z, pbv.w };
        const float fww[4] = { fwv.x, fwv.y, fwv.z, fwv.w };
        #pragma unroll
        for (int r = 0; r < 4; ++r)
            s0 += fmaxf(pacc[m][r] + pbb[r], 0.f) * fww[r];
    }
    s0 += __shfl_xor(s0, 16);
    s0 += __shfl_xor(s0, 32);
    if (lane < 16) zred[cg][ng][lane] = s0;        // k = 16ng + lane
    __syncthreads();
    if (tid < 32) {
        const int kt = tid >> 4, kl = tid & 15;
        const float zz = zred[0][kt][kl] + zred[1][kt][kl]
                       + zred[2][kt][kl] + zred[3][kt][kl];
        const int kG = jt * 32 + tid;
        if (kG < KCH)
            out[b * KCH + kG] = (kG < nch_s) ? (zz + fcb[0]) : 0.f;
    }
}

// ================= fp32 fallback (round-3 verified) =================
#define TT   78
#define NTB  27
#define STRIDE 84

__device__ __forceinline__ void stage_w_fb(float* __restrict__ wtS,
                                           const float* __restrict__ wraw, int cc, int tid) {
    for (int i = tid; i < 6144; i += 256)
        wtS[i] = wraw[(i & 127) * 384 + cc * 3 + (i >> 7)];
}

__device__ __forceinline__ void conv_gemm_fb(float (&acc)[10][4],
                                             const float* __restrict__ wraw,
                                             const float* __restrict__ hAp,
                                             float* __restrict__ wtS,
                                             int tid, int c0, int tbase) {
    #pragma unroll
    for (int i = 0; i < 10; ++i)
        #pragma unroll
        for (int q = 0; q < 4; ++q) acc[i][q] = 0.f;
    for (int cc = 0; cc < HH; cc += 16) {
        __syncthreads();
        stage_w_fb(wtS, wraw, cc, tid);
        __syncthreads();
        for (int ci = 0; ci < 16; ++ci) {
            float hr[12];
            #pragma unroll
            for (int j = 0; j < 12; ++j) hr[j] = hAp[(cc + ci) * STRIDE + tbase + j];
            #pragma unroll
            for (int tap = 0; tap < 3; ++tap) {
                const float4 w = *(const float4*)&wtS[((ci * 3 + tap) << 7) + c0];
                #pragma unroll
                for (int i = 0; i < 10; ++i) {
                    const float h = hr[i + tap];
                    acc[i][0] = fmaf(h, w.x, acc[i][0]);
                    acc[i][1] = fmaf(h, w.y, acc[i][1]);
                    acc[i][2] = fmaf(h, w.z, acc[i][2]);
                    acc[i][3] = fmaf(h, w.w, acc[i][3]);
                }
            }
        }
    }
}

__global__ __launch_bounds__(256, 2)
void fused_pd(const float* __restrict__ x, const int* __restrict__ seq,
              const float* __restrict__ w0, const float* __restrict__ b0,
              const float* __restrict__ w1raw, const float* __restrict__ b1,
              const float* __restrict__ w2raw, const float* __restrict__ b2,
              const float* __restrict__ bng, const float* __restrict__ bnb,
              const float* __restrict__ bnm, const float* __restrict__ bnv,
              const float* __restrict__ pwraw, const float* __restrict__ pb,
              const float* __restrict__ fcw, const float* __restrict__ fcb,
              float* __restrict__ out) {
    __shared__ __align__(16) float hA[HH * STRIDE];
    __shared__ __align__(16) float wtS[6144];
    __shared__ __align__(16) float xsf[TT + 8];
    __shared__ int nch_s;

    const int tid = threadIdx.x;
    const int b  = blockIdx.x / NTB;
    const int jt = blockIdx.x - b * NTB;
    const int t0 = jt * TT;

    for (int j = tid; j < TT + 6; j += 256) {
        const int t = t0 - 3 + j;
        xsf[j] = (t >= 0 && t < S) ? x[b * S + t] : 0.f;
    }
    if (tid == 0) nch_s = read_seqlen(seq, b) / 3;

    const int cch = tid & 127;
    const float w0a = w0[cch * 3 + 0], w0b = w0[cch * 3 + 1], w0c = w0[cch * 3 + 2];
    const float bb0 = b0[cch];
    const float a0 = bng[cch] * rsqrtf(bnv[cch] + EPS);
    const float d0 = bnb[cch] - bnm[cch] * a0;
    __syncthreads();

    for (int i = tid; i < (TT + 4) * HH; i += 256) {
        const int ttl = i >> 7;
        const int t = t0 - 2 + ttl;
        float v = 0.f;
        if (t >= 0 && t < S) {
            float sa = fmaf(xsf[ttl + 2], w0c, fmaf(xsf[ttl + 1], w0b, fmaf(xsf[ttl], w0a, bb0)));
            v = fmaf(fmaxf(sa, 0.f), a0, d0);
        }
        hA[cch * STRIDE + ttl] = v;
    }

    const int cg = tid & 31, tg = tid >> 5;
    const int c0 = cg * 4;
    const int tbase = tg * 10;
    float acc[10][4];

    conv_gemm_fb(acc, w1raw, hA, wtS, tid, c0, tbase);
    {
        const float4 bv = *(const float4*)&b1[c0];
        const float4 g  = *(const float4*)&bng[HH + c0];
        const float4 be = *(const float4*)&bnb[HH + c0];
        const float4 mn = *(const float4*)&bnm[HH + c0];
        const float4 vr = *(const float4*)&bnv[HH + c0];
        float av[4] = { g.x * rsqrtf(vr.x + EPS), g.y * rsqrtf(vr.y + EPS),
                        g.z * rsqrtf(vr.z + EPS), g.w * rsqrtf(vr.w + EPS) };
        float dv[4] = { be.x - mn.x * av[0], be.y - mn.y * av[1],
                        be.z - mn.z * av[2], be.w - mn.w * av[3] };
        float bb[4] = { bv.x, bv.y, bv.z, bv.w };
        __syncthreads();
        #pragma unroll
        for (int i = 0; i < 10; ++i) {
            const int tt2 = tbase + i;
            const int t = t0 - 1 + tt2;
            const bool ok = (t >= 0) && (t < S);
            #pragma unroll
            for (int q = 0; q < 4; ++q) {
                float v = 0.f;
                if (ok) v = fmaf(fmaxf(acc[i][q] + bb[q], 0.f), av[q], dv[q]);
                hA[(c0 + q) * STRIDE + tt2] = v;
            }
        }
        __syncthreads();
    }

    conv_gemm_fb(acc, w2raw, hA, wtS, tid, c0, tbase);
    {
        const float4 bv = *(const float4*)&b2[c0];
        const float4 g  = *(const float4*)&bng[2 * HH + c0];
        const float4 be = *(const float4*)&bnb[2 * HH + c0];
        const float4 mn = *(const float4*)&bnm[2 * HH + c0];
        const float4 vr = *(const float4*)&bnv[2 * HH + c0];
        float av[4] = { g.x * rsqrtf(vr.x + EPS), g.y * rsqrtf(vr.y + EPS),
                        g.z * rsqrtf(vr.z + EPS), g.w * rsqrtf(vr.w + EPS) };
        float dv[4] = { be.x - mn.x * av[0], be.y - mn.y * av[1],
                        be.z - mn.z * av[2], be.w - mn.w * av[3] };
        float bb[4] = { bv.x, bv.y, bv.z, bv.w };
        __syncthreads();
        #pragma unroll
        for (int i = 0; i < 10; ++i) {
            const int tt3 = tbase + i;
            if (tt3 < TT) {
                const int t = t0 + tt3;
                #pragma unroll
                for (int q = 0; q < 4; ++q) {
                    float vv = 0.f;
                    if (t < S) vv = fmaf(fmaxf(acc[i][q] + bb[q], 0.f), av[q], dv[q]);
                    hA[(c0 + q) * STRIDE + tt3] = vv;
                }
            }
        }
        __syncthreads();
    }

    const int og = tid & 31, kg = tid >> 5;
    const int oo = og * 4;
    float pacc[4][4];
    #pragma unroll
    for (int j = 0; j < 4; ++j)
        #pragma unroll
        for (int q = 0; q < 4; ++q) pacc[j][q] = 0.f;

    for (int hc = 0; hc < HH; hc += 16) {
        __syncthreads();
        stage_w_fb(wtS, pwraw, hc, tid);
        __syncthreads();
        for (int h = 0; h < 16; ++h) {
            #pragma unroll
            for (int tap = 0; tap < 3; ++tap) {
                const float4 w = *(const float4*)&wtS[((h * 3 + tap) << 7) + oo];
                #pragma unroll
                for (int j = 0; j < 4; ++j) {
                    int kl = kg * 4 + j; kl = (kl > 25) ? 25 : kl;
                    const float hv = hA[(hc + h) * STRIDE + 3 * kl + tap];
                    pacc[j][0] = fmaf(hv, w.x, pacc[j][0]);
                    pacc[j][1] = fmaf(hv, w.y, pacc[j][1]);
                    pacc[j][2] = fmaf(hv, w.z, pacc[j][2]);
                    pacc[j][3] = fmaf(hv, w.w, pacc[j][3]);
                }
            }
        }
    }

    const float fcb0 = fcb[0];
    const float4 pbv = *(const float4*)&pb[oo];
    const float4 fwv = *(const float4*)&fcw[oo];
    const int nch = nch_s;
    #pragma unroll
    for (int j = 0; j < 4; ++j) {
        float s = fmaxf(pacc[j][0] + pbv.x, 0.f) * fwv.x
                + fmaxf(pacc[j][1] + pbv.y, 0.f) * fwv.y
                + fmaxf(pacc[j][2] + pbv.z, 0.f) * fwv.z
                + fmaxf(pacc[j][3] + pbv.w, 0.f) * fwv.w;
        #pragma unroll
        for (int m = 1; m < 32; m <<= 1) s += __shfl_xor(s, m, 64);
        if (og == 0) {
            const int kl = kg * 4 + j;
            const int kG = jt * 26 + kl;
            if (kl < 26 && kG < KCH)
                out[b * KCH + kG] = (kG < nch) ? (s + fcb0) : 0.f;
        }
    }
}

extern "C" void kernel_launch(void* const* d_in, const int* in_sizes, int n_in,
                              void* d_out, int out_size, void* d_ws, size_t ws_size,
                              hipStream_t stream) {
    (void)in_sizes; (void)n_in; (void)out_size;
    const float* x    = (const float*)d_in[0];
    const int*   seq  = (const int*)d_in[1];
    const float* w0   = (const float*)d_in[2];
    const float* b0   = (const float*)d_in[3];
    const float* w1   = (const float*)d_in[4];
    const float* b1   = (const float*)d_in[5];
    const float* w2   = (const float*)d_in[6];
    const float* b2   = (const float*)d_in[7];
    const float* bng  = (const float*)d_in[8];
    const float* bnb  = (const float*)d_in[9];
    const float* bnm  = (const float*)d_in[10];
    const float* bnv  = (const float*)d_in[11];
    const float* pw   = (const float*)d_in[12];
    const float* pb   = (const float*)d_in[13];
    const float* fcw  = (const float*)d_in[14];
    const float* fcb  = (const float*)d_in[15];
    float* out = (float*)d_out;

    const size_t need = (size_t)3 * 12 * 8 * 1024;   // 294912 B of packed frags
    if (ws_size >= need) {
        unsigned short* wpk = (unsigned short*)d_ws;
        pack_w_frags<<<72, 256, 0, stream>>>(w1, w2, pw, wpk);
        fused_mfma<<<BB * NTB2, 512, 0, stream>>>(x, seq, w0, b0, b1, b2,
                                                  bng, bnb, bnm, bnv,
                                                  pb, fcw, fcb, wpk, out);
    } else {
        fused_pd<<<BB * NTB, 256, 0, stream>>>(x, seq, w0, b0, w1, b1, w2, b2,
                                               bng, bnb, bnm, bnv, pw, pb, fcw, fcb,
                                               out);
    }
}